// Round 11
// baseline (193.185 us; speedup 1.0000x reference)
//
#include <hip/hip_runtime.h>

typedef float f32x4 __attribute__((ext_vector_type(4)));
typedef short s16x8 __attribute__((ext_vector_type(8)));
typedef unsigned short u16;
typedef unsigned int u32;

#define MFMA16 __builtin_amdgcn_mfma_f32_16x16x32_bf16
#define SCALE 0.17677669529663687f  // 32^-0.5

__device__ __forceinline__ u16 f2b(float f) {
  union { float f; unsigned u; } x; x.f = f;
  unsigned r = x.u + 0x7fffu + ((x.u >> 16) & 1u);
  return (u16)(r >> 16);
}
__device__ __forceinline__ float b2f(u16 s) {
  union { unsigned u; float f; } x; x.u = ((unsigned)s) << 16;
  return x.f;
}
// pack two f32 -> u32 of two bf16 (low = a, high = b), TRUNCATE, 1 inst
__device__ __forceinline__ u32 pkt(float a, float b) {
  return __builtin_amdgcn_perm(__builtin_bit_cast(u32, b),
                               __builtin_bit_cast(u32, a), 0x07060302u);
}
__device__ __forceinline__ u32 bperm(int idx, u32 src) {
  return (u32)__builtin_amdgcn_ds_bpermute(idx, (int)src);
}
__device__ __forceinline__ s16x8 mk8(u32 a, u32 b, u32 c, u32 d) {
  union { u32 w[4]; s16x8 v; } u;
  u.w[0] = a; u.w[1] = b; u.w[2] = c; u.w[3] = d;
  return u.v;
}

// ---------------- weight transpose + bf16 cast: WT[j][d] = bf16(W[d][j]) ----
__global__ __launch_bounds__(256) void wtrans_kernel(
    const float* __restrict__ Wq, const float* __restrict__ Wk,
    const float* __restrict__ Wv, const float* __restrict__ Wo,
    u16* __restrict__ WqT, u16* __restrict__ WkT,
    u16* __restrict__ WvT, u16* __restrict__ WoT) {
  const float* src; u16* dst;
  switch (blockIdx.x) {
    case 0: src = Wq; dst = WqT; break;
    case 1: src = Wk; dst = WkT; break;
    case 2: src = Wv; dst = WvT; break;
    default: src = Wo; dst = WoT; break;
  }
  int j = blockIdx.y;
  int d = threadIdx.x;
  dst[j * 256 + d] = f2b(src[d * 256 + j]);
}

// ---------------- xq passthrough (output 1) --------------------------------
__global__ __launch_bounds__(256) void copyxq_kernel(const float* __restrict__ xq,
                                                     float* __restrict__ dst) {
  int i = blockIdx.x * 256 + threadIdx.x;
  dst[i] = xq[i];
}

// ---------------- QKV projection: bf16 MFMA GEMM ---------------------------
__global__ __launch_bounds__(256) void proj_kernel(
    const float* __restrict__ zq, const float* __restrict__ zk,
    const float* __restrict__ zv,
    const u16* __restrict__ WqT, const u16* __restrict__ WkT,
    const u16* __restrict__ WvT,
    u16* __restrict__ qb, u16* __restrict__ kb, u16* __restrict__ vT) {
  const int mat = blockIdx.z;
  const float* Z = (mat == 0) ? zq : (mat == 1) ? zk : zv;
  const u16* WT = (mat == 0) ? WqT : (mat == 1) ? WkT : WvT;
  const int n0 = blockIdx.x * 64;
  const int j0 = blockIdx.y * 64;
  const int tid = threadIdx.x;
  const int lane = tid & 63, wid = tid >> 6;
  const int l15 = lane & 15, lg = lane >> 4;
  const int wn = wid & 1, wj = wid >> 1;

  __shared__ u16 As[64][40];
  __shared__ u16 Bs[64][40];

  f32x4 acc[2][2];
  #pragma unroll
  for (int a = 0; a < 2; ++a)
    #pragma unroll
    for (int b = 0; b < 2; ++b) acc[a][b] = (f32x4){0.f, 0.f, 0.f, 0.f};

  for (int ks = 0; ks < 8; ++ks) {
    const int d0 = ks * 32;
    const int r = tid >> 2, cb = (tid & 3) * 8;
    const float* zsrc = &Z[(size_t)(n0 + r) * 256 + d0 + cb];
    s16x8 t;
    #pragma unroll
    for (int j = 0; j < 8; ++j) t[j] = (short)f2b(zsrc[j]);
    *(s16x8*)&As[r][cb] = t;
    *(s16x8*)&Bs[r][cb] = *(const s16x8*)&WT[(size_t)(j0 + r) * 256 + d0 + cb];
    __syncthreads();
    s16x8 a0 = *(const s16x8*)&As[wn * 32 + l15][lg * 8];
    s16x8 a1 = *(const s16x8*)&As[wn * 32 + 16 + l15][lg * 8];
    s16x8 b0 = *(const s16x8*)&Bs[wj * 32 + l15][lg * 8];
    s16x8 b1 = *(const s16x8*)&Bs[wj * 32 + 16 + l15][lg * 8];
    acc[0][0] = MFMA16(a0, b0, acc[0][0], 0, 0, 0);
    acc[0][1] = MFMA16(a0, b1, acc[0][1], 0, 0, 0);
    acc[1][0] = MFMA16(a1, b0, acc[1][0], 0, 0, 0);
    acc[1][1] = MFMA16(a1, b1, acc[1][1], 0, 0, 0);
    __syncthreads();
  }
  #pragma unroll
  for (int sn = 0; sn < 2; ++sn)
    #pragma unroll
    for (int sj = 0; sj < 2; ++sj)
      #pragma unroll
      for (int i = 0; i < 4; ++i) {
        int n = n0 + wn * 32 + sn * 16 + lg * 4 + i;
        int j = j0 + wj * 32 + sj * 16 + l15;
        float av = acc[sn][sj][i];
        if (mat == 0) av *= SCALE;
        u16 val = f2b(av);
        if (mat == 0) {
          qb[(size_t)n * 256 + j] = val;
        } else if (mat == 1) {
          kb[(size_t)n * 256 + j] = val;
        } else {
          int mm = n >> 10, nn = n & 1023;
          vT[((size_t)(mm * 256 + j)) * 1024 + nn] = val;
        }
      }
}

// ---------------- fused TE attention: 1 wave per block, barrier-free -------
// Block = 1 wave: 16 queries x (1024/KZ) keys of one m. No inter-wave deps.
// Per 32-key superblock: 2x(dots MFMA + MFMA-MLP -> private P_s) then
// PV over all 8 heads (16x16x32, K=32) + L via ones-A-frag MFMA.
__global__ __launch_bounds__(64, 3) void attn_kernel(
    const u16* __restrict__ qb, const u16* __restrict__ kb,
    const u16* __restrict__ vT,
    const float* __restrict__ xq, const float* __restrict__ xkv,
    const float* __restrict__ W1, const float* __restrict__ b1,
    const float* __restrict__ W2, const float* __restrict__ b2,
    u16* __restrict__ preP, float* __restrict__ Lb) {
  const int m = blockIdx.y;
  const int q0 = blockIdx.x * 16;
  const int kzi = blockIdx.z;
  const int keys_per = 1024 / gridDim.z;
  const int nsuper = keys_per >> 5;
  const int lane = threadIdx.x & 63;
  const int l15 = lane & 15;
  const int lg = lane >> 4;

  u16* myPre = preP + (size_t)kzi * (8192 * 256);
  float* myL = Lb + (size_t)kzi * (8192 * 8);

  __shared__ u16 P_s[8][16][40];  // [h][q][32k + pad8]; rows 80 B (16B-mult)

  // resident W1^T A-frags, channel-permuted (sigma(b,r)=8*(r>>2)+4b+(r&3))
  s16x8 w1a[2];
  #pragma unroll
  for (int cblk = 0; cblk < 2; ++cblk) {
    const int c = 8 * (l15 >> 2) + 4 * cblk + (l15 & 3);
    #pragma unroll
    for (int j = 0; j < 8; ++j) {
      const int dim = lg * 8 + j;
      u16 v = 0;
      if (dim < 10) v = f2b(W1[dim * 32 + c]);
      else if (dim == 10) v = f2b(b1[c]);
      w1a[cblk][j] = (short)v;
    }
  }
  // resident W2^T A-frag: A[row=h=l15 (<8)][K=c=lg*8+j]
  s16x8 w2a;
  #pragma unroll
  for (int j = 0; j < 8; ++j) {
    const int c = lg * 8 + j;
    w2a[j] = (short)((l15 < 8) ? f2b(W2[c * 8 + l15]) : (u16)0);
  }
  float b2r[4];
  #pragma unroll
  for (int i = 0; i < 4; ++i) b2r[i] = b2[(lg & 1) * 4 + i];

  const int idx10 = (l15 + 0) * 4;
  const int idx11 = (l15 + 16) * 4;
  const int idx12 = (l15 + 32) * 4;
  const int idx13 = (l15 + 48) * 4;
  const u32 u1base = (lg == 1) ? 0x00003F80u : 0u;
  const bool lglo = (lg < 2);

  s16x8 onesA;  // all-ones A-frag for L-sum MFMA
  #pragma unroll
  for (int j = 0; j < 8; ++j) onesA[j] = (short)0x3F80;

  f32x4 acc2[16];
  #pragma unroll
  for (int dc = 0; dc < 16; ++dc) acc2[dc] = (f32x4){0.f, 0.f, 0.f, 0.f};
  float Lacc[8];
  #pragma unroll
  for (int h = 0; h < 8; ++h) Lacc[h] = 0.0f;
  const f32x4 Z4 = (f32x4){0.f, 0.f, 0.f, 0.f};

  for (int sb = 0; sb < nsuper; ++sb) {
    const int kgb = kzi * keys_per + sb * 32;
    #pragma unroll
    for (int half = 0; half < 2; ++half) {
      const int kg = kgb + half * 16;
      const float2 xk2 = *(const float2*)&xkv[((size_t)(m * 1024 + kg + l15)) * 2];

      // dots: 8 MFMA (per head), Q/K frags from global (L2)
      u32 dpk[4][4];
      {
        f32x4 dacc[8];
        #pragma unroll
        for (int h = 0; h < 8; ++h) {
          const s16x8 a = *(const s16x8*)&qb[((size_t)(m * 1024 + q0 + l15)) * 256 + h * 32 + lg * 8];
          const s16x8 b = *(const s16x8*)&kb[((size_t)(m * 1024 + kg + l15)) * 256 + h * 32 + lg * 8];
          dacc[h] = MFMA16(a, b, Z4, 0, 0, 0);
        }
        #pragma unroll
        for (int i = 0; i < 4; ++i)
          #pragma unroll
          for (int j = 0; j < 4; ++j)
            dpk[i][j] = pkt(dacc[2 * j][i], dacc[2 * j + 1][i]);
      }

      // MLP over 16 pair-groups (qg = one q x this wave's 16 keys)
      #pragma unroll
      for (int qg = 0; qg < 16; ++qg) {
        const int isrc = qg & 3;
        const int idxq = (qg >> 2) == 0 ? idx10 : (qg >> 2) == 1 ? idx11
                       : (qg >> 2) == 2 ? idx12 : idx13;
        const u32 p0 = bperm(idxq, dpk[isrc][0]);
        const u32 p1 = bperm(idxq, dpk[isrc][1]);
        const u32 p2 = bperm(idxq, dpk[isrc][2]);
        const u32 p3 = bperm(idxq, dpk[isrc][3]);
        const float2 xq2 = *(const float2*)&xq[((size_t)(m * 1024 + q0 + qg)) * 2];
        const u32 dqpair = pkt(xq2.x - xk2.x, xq2.y - xk2.y);
        const u32 u0 = (lg == 0) ? dqpair : ((lg == 1) ? p3 : 0u);
        const u32 u1 = (lg == 0) ? p0 : u1base;
        const u32 u2 = (lg == 0) ? p1 : 0u;
        const u32 u3 = (lg == 0) ? p2 : 0u;
        const s16x8 bf1 = mk8(u0, u1, u2, u3);
        const f32x4 h0 = MFMA16(w1a[0], bf1, Z4, 0, 0, 0);
        const f32x4 h1 = MFMA16(w1a[1], bf1, Z4, 0, 0, 0);
        const s16x8 bf2 = mk8(pkt(fmaxf(h0[0], 0.f), fmaxf(h0[1], 0.f)),
                              pkt(fmaxf(h0[2], 0.f), fmaxf(h0[3], 0.f)),
                              pkt(fmaxf(h1[0], 0.f), fmaxf(h1[1], 0.f)),
                              pkt(fmaxf(h1[2], 0.f), fmaxf(h1[3], 0.f)));
        const f32x4 Lg = MFMA16(w2a, bf2, Z4, 0, 0, 0);
        if (lglo) {
          #pragma unroll
          for (int i = 0; i < 4; ++i) {
            const float e = __expf(Lg[i] + b2r[i]);
            P_s[lg * 4 + i][qg][half * 16 + l15] =
                (u16)(__builtin_bit_cast(unsigned, e) >> 16);
          }
        }
      }
    }
    __syncthreads();  // single-wave block: just a waitcnt, near-free

    // PV (16x16x32, K=32 keys of this superblock) + L (ones-A trick)
    s16x8 paf[8];
    #pragma unroll
    for (int h = 0; h < 8; ++h)
      paf[h] = *(const s16x8*)&P_s[h][l15][lg * 8];
    #pragma unroll
    for (int dc = 0; dc < 16; ++dc) {
      const s16x8 bv = *(const s16x8*)&vT[((size_t)(m * 256 + dc * 16 + l15)) * 1024 + kgb + lg * 8];
      acc2[dc] = MFMA16(paf[dc >> 1], bv, acc2[dc], 0, 0, 0);
    }
    #pragma unroll
    for (int h = 0; h < 8; ++h) {
      const f32x4 lc = MFMA16(onesA, paf[h], Z4, 0, 0, 0);
      Lacc[h] += lc[0];
    }
    __syncthreads();  // protect P_s reuse next superblock
  }

  // epilogue: store bf16 partial O and f32 partial L
  #pragma unroll
  for (int dc = 0; dc < 16; ++dc)
    #pragma unroll
    for (int i = 0; i < 4; ++i)
      myPre[((size_t)(m * 1024 + q0 + lg * 4 + i)) * 256 + dc * 16 + l15] = f2b(acc2[dc][i]);
  if (lg == 0) {
    #pragma unroll
    for (int h = 0; h < 8; ++h)
      myL[((size_t)(m * 1024 + q0 + l15)) * 8 + h] = Lacc[h];
  }
}

// ---------------- output projection with KZ-way partial combine ------------
__global__ __launch_bounds__(256) void outp_kernel(
    const u16* __restrict__ preP, const float* __restrict__ Lb,
    const u16* __restrict__ WoT,
    const float* __restrict__ bout, float* __restrict__ out, int kz) {
  const int n0 = blockIdx.x * 64;
  const int j0 = blockIdx.y * 64;
  const int tid = threadIdx.x;
  const int lane = tid & 63, wid = tid >> 6;
  const int l15 = lane & 15, lg = lane >> 4;
  const int wn = wid & 1, wj = wid >> 1;
  __shared__ u16 As[64][40];
  __shared__ u16 Bs[64][40];
  f32x4 acc[2][2];
  #pragma unroll
  for (int a = 0; a < 2; ++a)
    #pragma unroll
    for (int b = 0; b < 2; ++b) acc[a][b] = (f32x4){0.f, 0.f, 0.f, 0.f};

  const size_t PSTRIDE = (size_t)8192 * 256;
  const size_t LSTRIDE = (size_t)8192 * 8;

  for (int ks = 0; ks < 8; ++ks) {
    const int d0 = ks * 32;
    const int r = tid >> 2, cb = (tid & 3) * 8;
    const size_t row = (size_t)(n0 + r);
    float Ls = 0.0f;
    for (int s = 0; s < kz; ++s) Ls += Lb[s * LSTRIDE + row * 8 + ks];
    const float inv = 1.0f / Ls;
    float a8[8] = {0.f, 0.f, 0.f, 0.f, 0.f, 0.f, 0.f, 0.f};
    for (int s = 0; s < kz; ++s) {
      const s16x8 p = *(const s16x8*)&preP[s * PSTRIDE + row * 256 + d0 + cb];
      #pragma unroll
      for (int j = 0; j < 8; ++j) a8[j] += b2f((u16)p[j]);
    }
    s16x8 t;
    #pragma unroll
    for (int j = 0; j < 8; ++j) t[j] = (short)f2b(a8[j] * inv);
    *(s16x8*)&As[r][cb] = t;
    *(s16x8*)&Bs[r][cb] = *(const s16x8*)&WoT[(size_t)(j0 + r) * 256 + d0 + cb];
    __syncthreads();
    s16x8 a0 = *(const s16x8*)&As[wn * 32 + l15][lg * 8];
    s16x8 a1 = *(const s16x8*)&As[wn * 32 + 16 + l15][lg * 8];
    s16x8 b0 = *(const s16x8*)&Bs[wj * 32 + l15][lg * 8];
    s16x8 b1 = *(const s16x8*)&Bs[wj * 32 + 16 + l15][lg * 8];
    acc[0][0] = MFMA16(a0, b0, acc[0][0], 0, 0, 0);
    acc[0][1] = MFMA16(a0, b1, acc[0][1], 0, 0, 0);
    acc[1][0] = MFMA16(a1, b0, acc[1][0], 0, 0, 0);
    acc[1][1] = MFMA16(a1, b1, acc[1][1], 0, 0, 0);
    __syncthreads();
  }
  #pragma unroll
  for (int sn = 0; sn < 2; ++sn)
    #pragma unroll
    for (int sj = 0; sj < 2; ++sj)
      #pragma unroll
      for (int i = 0; i < 4; ++i) {
        int n = n0 + wn * 32 + sn * 16 + lg * 4 + i;
        int j = j0 + wj * 32 + sj * 16 + l15;
        out[(size_t)n * 256 + j] = acc[sn][sj][i] + bout[j];
      }
}

extern "C" void kernel_launch(void* const* d_in, const int* in_sizes, int n_in,
                              void* d_out, int out_size, void* d_ws, size_t ws_size,
                              hipStream_t stream) {
  const float* zq = (const float*)d_in[0];
  const float* zk = (const float*)d_in[1];
  const float* zv = (const float*)d_in[2];
  const float* xq = (const float*)d_in[3];
  const float* xkv = (const float*)d_in[4];
  const float* Wq = (const float*)d_in[5];
  const float* Wk = (const float*)d_in[6];
  const float* Wv = (const float*)d_in[7];
  const float* Wo = (const float*)d_in[8];
  const float* bout = (const float*)d_in[9];
  const float* W1 = (const float*)d_in[10];
  const float* b1 = (const float*)d_in[11];
  const float* W2 = (const float*)d_in[12];
  const float* b2 = (const float*)d_in[13];
  float* out = (float*)d_out;

  const size_t MB = (size_t)1 << 20;
  const int KZ = (ws_size >= 48 * MB) ? 8 : 4;
  char* ws = (char*)d_ws;
  u16* qb   = (u16*)(ws + 0 * MB);
  u16* kb   = (u16*)(ws + 4 * MB);
  u16* vT   = (u16*)(ws + 8 * MB);
  u16* preP = (u16*)(ws + 12 * MB);                       // KZ x 4 MB bf16
  float* Lb = (float*)(ws + (12 + (size_t)KZ * 4) * MB);  // KZ x 256 KB f32
  char* wbase = ws + (12 + (size_t)KZ * 4) * MB + (size_t)KZ * (256 << 10);
  u16* WqT  = (u16*)(wbase + 0 * (128 << 10));
  u16* WkT  = (u16*)(wbase + 1 * (128 << 10));
  u16* WvT  = (u16*)(wbase + 2 * (128 << 10));
  u16* WoT  = (u16*)(wbase + 3 * (128 << 10));

  wtrans_kernel<<<dim3(4, 256), dim3(256), 0, stream>>>(Wq, Wk, Wv, Wo, WqT, WkT, WvT, WoT);
  proj_kernel<<<dim3(128, 4, 3), dim3(256), 0, stream>>>(zq, zk, zv, WqT, WkT, WvT, qb, kb, vT);
  attn_kernel<<<dim3(64, 8, KZ), dim3(64), 0, stream>>>(qb, kb, vT, xq, xkv, W1, b1, W2, b2, preP, Lb);
  outp_kernel<<<dim3(128, 4), dim3(256), 0, stream>>>(preP, Lb, WoT, bout, out, KZ);
  copyxq_kernel<<<dim3(64), dim3(256), 0, stream>>>(xq, out + (size_t)8 * 1024 * 256);
}

// Round 12
// 152.333 us; speedup vs baseline: 1.2682x; 1.2682x over previous
//
#include <hip/hip_runtime.h>

typedef float f32x4 __attribute__((ext_vector_type(4)));
typedef short s16x8 __attribute__((ext_vector_type(8)));
typedef unsigned short u16;
typedef unsigned int u32;

#define MFMA16 __builtin_amdgcn_mfma_f32_16x16x32_bf16
#define SCALE 0.17677669529663687f  // 32^-0.5

__device__ __forceinline__ u16 f2b(float f) {
  union { float f; unsigned u; } x; x.f = f;
  unsigned r = x.u + 0x7fffu + ((x.u >> 16) & 1u);
  return (u16)(r >> 16);
}
__device__ __forceinline__ float b2f(u16 s) {
  union { unsigned u; float f; } x; x.u = ((unsigned)s) << 16;
  return x.f;
}
// pack two f32 -> u32 of two bf16 (low = a, high = b), TRUNCATE, 1 inst
__device__ __forceinline__ u32 pkt(float a, float b) {
  return __builtin_amdgcn_perm(__builtin_bit_cast(u32, b),
                               __builtin_bit_cast(u32, a), 0x07060302u);
}
__device__ __forceinline__ u32 bperm(int idx, u32 src) {
  return (u32)__builtin_amdgcn_ds_bpermute(idx, (int)src);
}
__device__ __forceinline__ s16x8 mk8(u32 a, u32 b, u32 c, u32 d) {
  union { u32 w[4]; s16x8 v; } u;
  u.w[0] = a; u.w[1] = b; u.w[2] = c; u.w[3] = d;
  return u.v;
}

// ---------------- weight transpose + bf16 cast: WT[j][d] = bf16(W[d][j]) ----
__global__ __launch_bounds__(256) void wtrans_kernel(
    const float* __restrict__ Wq, const float* __restrict__ Wk,
    const float* __restrict__ Wv, const float* __restrict__ Wo,
    u16* __restrict__ WqT, u16* __restrict__ WkT,
    u16* __restrict__ WvT, u16* __restrict__ WoT) {
  const float* src; u16* dst;
  switch (blockIdx.x) {
    case 0: src = Wq; dst = WqT; break;
    case 1: src = Wk; dst = WkT; break;
    case 2: src = Wv; dst = WvT; break;
    default: src = Wo; dst = WoT; break;
  }
  int j = blockIdx.y;
  int d = threadIdx.x;
  dst[j * 256 + d] = f2b(src[d * 256 + j]);
}

// ---------------- xq passthrough (output 1) --------------------------------
__global__ __launch_bounds__(256) void copyxq_kernel(const float* __restrict__ xq,
                                                     float* __restrict__ dst) {
  int i = blockIdx.x * 256 + threadIdx.x;
  dst[i] = xq[i];
}

// ---------------- QKV projection: bf16 MFMA GEMM ---------------------------
__global__ __launch_bounds__(256) void proj_kernel(
    const float* __restrict__ zq, const float* __restrict__ zk,
    const float* __restrict__ zv,
    const u16* __restrict__ WqT, const u16* __restrict__ WkT,
    const u16* __restrict__ WvT,
    u16* __restrict__ qb, u16* __restrict__ kb, u16* __restrict__ vT) {
  const int mat = blockIdx.z;
  const float* Z = (mat == 0) ? zq : (mat == 1) ? zk : zv;
  const u16* WT = (mat == 0) ? WqT : (mat == 1) ? WkT : WvT;
  const int n0 = blockIdx.x * 64;
  const int j0 = blockIdx.y * 64;
  const int tid = threadIdx.x;
  const int lane = tid & 63, wid = tid >> 6;
  const int l15 = lane & 15, lg = lane >> 4;
  const int wn = wid & 1, wj = wid >> 1;

  __shared__ u16 As[64][40];
  __shared__ u16 Bs[64][40];

  f32x4 acc[2][2];
  #pragma unroll
  for (int a = 0; a < 2; ++a)
    #pragma unroll
    for (int b = 0; b < 2; ++b) acc[a][b] = (f32x4){0.f, 0.f, 0.f, 0.f};

  for (int ks = 0; ks < 8; ++ks) {
    const int d0 = ks * 32;
    const int r = tid >> 2, cb = (tid & 3) * 8;
    const float* zsrc = &Z[(size_t)(n0 + r) * 256 + d0 + cb];
    s16x8 t;
    #pragma unroll
    for (int j = 0; j < 8; ++j) t[j] = (short)f2b(zsrc[j]);
    *(s16x8*)&As[r][cb] = t;
    *(s16x8*)&Bs[r][cb] = *(const s16x8*)&WT[(size_t)(j0 + r) * 256 + d0 + cb];
    __syncthreads();
    s16x8 a0 = *(const s16x8*)&As[wn * 32 + l15][lg * 8];
    s16x8 a1 = *(const s16x8*)&As[wn * 32 + 16 + l15][lg * 8];
    s16x8 b0 = *(const s16x8*)&Bs[wj * 32 + l15][lg * 8];
    s16x8 b1 = *(const s16x8*)&Bs[wj * 32 + 16 + l15][lg * 8];
    acc[0][0] = MFMA16(a0, b0, acc[0][0], 0, 0, 0);
    acc[0][1] = MFMA16(a0, b1, acc[0][1], 0, 0, 0);
    acc[1][0] = MFMA16(a1, b0, acc[1][0], 0, 0, 0);
    acc[1][1] = MFMA16(a1, b1, acc[1][1], 0, 0, 0);
    __syncthreads();
  }
  #pragma unroll
  for (int sn = 0; sn < 2; ++sn)
    #pragma unroll
    for (int sj = 0; sj < 2; ++sj)
      #pragma unroll
      for (int i = 0; i < 4; ++i) {
        int n = n0 + wn * 32 + sn * 16 + lg * 4 + i;
        int j = j0 + wj * 32 + sj * 16 + l15;
        float av = acc[sn][sj][i];
        if (mat == 0) av *= SCALE;
        u16 val = f2b(av);
        if (mat == 0) {
          qb[(size_t)n * 256 + j] = val;
        } else if (mat == 1) {
          kb[(size_t)n * 256 + j] = val;
        } else {
          int mm = n >> 10, nn = n & 1023;
          vT[((size_t)(mm * 256 + j)) * 1024 + nn] = val;
        }
      }
}

// ---------------- fused TE attention: 4 waves/block, barrier-free loop -----
// 1024 blocks x 256 thr. Decode: m = bid&7 (XCD affinity), qblk=(bid>>3)&63,
// kzi = bid>>9. Wave wid owns keys [kzi*512 + wid*128, +128) for 16 queries:
// dots MFMA + MFMA-MLP -> wave-PRIVATE P_s -> PV all heads + ones-L MFMA.
// No __syncthreads in main loop (in-wave LDS ordering only). Epilogue: LDS
// reduction of 4 wave-partials -> one pre slice per kzi.
__global__ __launch_bounds__(256, 3) void attn_kernel(
    const u16* __restrict__ qb, const u16* __restrict__ kb,
    const u16* __restrict__ vT,
    const float* __restrict__ xq, const float* __restrict__ xkv,
    const float* __restrict__ W1, const float* __restrict__ b1,
    const float* __restrict__ W2, const float* __restrict__ b2,
    u16* __restrict__ preP, float* __restrict__ Lb) {
  const int bid = blockIdx.x;
  const int m = bid & 7;
  const int q0 = ((bid >> 3) & 63) * 16;
  const int kzi = bid >> 9;
  const int tid = threadIdx.x;
  const int wid = tid >> 6;
  const int lane = tid & 63;
  const int l15 = lane & 15;
  const int lg = lane >> 4;

  u16* myPre = preP + (size_t)kzi * (8192 * 256);
  float* myL = Lb + (size_t)kzi * (8192 * 8);

  // 4 waves x [8h][16q][40k] u16 = 40960 B; reused as reduction stage.
  __shared__ __align__(16) u16 lds[4 * 8 * 16 * 40];
  #define PP(w, h, q, k) lds[(((w) * 8 + (h)) * 16 + (q)) * 40 + (k)]

  // resident W1^T A-frags, channel-permuted (sigma(b,r)=8*(r>>2)+4b+(r&3))
  s16x8 w1a[2];
  #pragma unroll
  for (int cblk = 0; cblk < 2; ++cblk) {
    const int c = 8 * (l15 >> 2) + 4 * cblk + (l15 & 3);
    #pragma unroll
    for (int j = 0; j < 8; ++j) {
      const int dim = lg * 8 + j;
      u16 v = 0;
      if (dim < 10) v = f2b(W1[dim * 32 + c]);
      else if (dim == 10) v = f2b(b1[c]);
      w1a[cblk][j] = (short)v;
    }
  }
  // resident W2^T A-frag: A[row=h=l15 (<8)][K=c=lg*8+j]
  s16x8 w2a;
  #pragma unroll
  for (int j = 0; j < 8; ++j) {
    const int c = lg * 8 + j;
    w2a[j] = (short)((l15 < 8) ? f2b(W2[c * 8 + l15]) : (u16)0);
  }
  float b2r[4];
  #pragma unroll
  for (int i = 0; i < 4; ++i) b2r[i] = b2[(lg & 1) * 4 + i];

  const int idx10 = (l15 + 0) * 4;
  const int idx11 = (l15 + 16) * 4;
  const int idx12 = (l15 + 32) * 4;
  const int idx13 = (l15 + 48) * 4;
  const u32 u1base = (lg == 1) ? 0x00003F80u : 0u;
  const bool lglo = (lg < 2);

  s16x8 onesA;
  #pragma unroll
  for (int j = 0; j < 8; ++j) onesA[j] = (short)0x3F80;

  f32x4 acc2[16];
  #pragma unroll
  for (int dc = 0; dc < 16; ++dc) acc2[dc] = (f32x4){0.f, 0.f, 0.f, 0.f};
  float Lacc[8];
  #pragma unroll
  for (int h = 0; h < 8; ++h) Lacc[h] = 0.0f;
  const f32x4 Z4 = (f32x4){0.f, 0.f, 0.f, 0.f};

  const int kbase = kzi * 512 + wid * 128;

  for (int sb = 0; sb < 4; ++sb) {
    const int kgb = kbase + sb * 32;
    #pragma unroll
    for (int half = 0; half < 2; ++half) {
      const int kg = kgb + half * 16;
      const float2 xk2 = *(const float2*)&xkv[((size_t)(m * 1024 + kg + l15)) * 2];

      // dots: 8 MFMA (per head), Q/K frags from global (L2)
      u32 dpk[4][4];
      {
        f32x4 dacc[8];
        #pragma unroll
        for (int h = 0; h < 8; ++h) {
          const s16x8 a = *(const s16x8*)&qb[((size_t)(m * 1024 + q0 + l15)) * 256 + h * 32 + lg * 8];
          const s16x8 b = *(const s16x8*)&kb[((size_t)(m * 1024 + kg + l15)) * 256 + h * 32 + lg * 8];
          dacc[h] = MFMA16(a, b, Z4, 0, 0, 0);
        }
        #pragma unroll
        for (int i = 0; i < 4; ++i)
          #pragma unroll
          for (int j = 0; j < 4; ++j)
            dpk[i][j] = pkt(dacc[2 * j][i], dacc[2 * j + 1][i]);
      }

      // MLP over 16 pair-groups (qg = one q x this wave's 16 keys)
      #pragma unroll 8
      for (int qg = 0; qg < 16; ++qg) {
        const int isrc = qg & 3;
        const int idxq = (qg >> 2) == 0 ? idx10 : (qg >> 2) == 1 ? idx11
                       : (qg >> 2) == 2 ? idx12 : idx13;
        const u32 p0 = bperm(idxq, dpk[isrc][0]);
        const u32 p1 = bperm(idxq, dpk[isrc][1]);
        const u32 p2 = bperm(idxq, dpk[isrc][2]);
        const u32 p3 = bperm(idxq, dpk[isrc][3]);
        const float2 xq2 = *(const float2*)&xq[((size_t)(m * 1024 + q0 + qg)) * 2];
        const u32 dqpair = pkt(xq2.x - xk2.x, xq2.y - xk2.y);
        const u32 u0 = (lg == 0) ? dqpair : ((lg == 1) ? p3 : 0u);
        const u32 u1 = (lg == 0) ? p0 : u1base;
        const u32 u2 = (lg == 0) ? p1 : 0u;
        const u32 u3 = (lg == 0) ? p2 : 0u;
        const s16x8 bf1 = mk8(u0, u1, u2, u3);
        const f32x4 h0 = MFMA16(w1a[0], bf1, Z4, 0, 0, 0);
        const f32x4 h1 = MFMA16(w1a[1], bf1, Z4, 0, 0, 0);
        const s16x8 bf2 = mk8(pkt(fmaxf(h0[0], 0.f), fmaxf(h0[1], 0.f)),
                              pkt(fmaxf(h0[2], 0.f), fmaxf(h0[3], 0.f)),
                              pkt(fmaxf(h1[0], 0.f), fmaxf(h1[1], 0.f)),
                              pkt(fmaxf(h1[2], 0.f), fmaxf(h1[3], 0.f)));
        const f32x4 Lg = MFMA16(w2a, bf2, Z4, 0, 0, 0);
        if (lglo) {
          #pragma unroll
          for (int i = 0; i < 4; ++i) {
            const float e = __expf(Lg[i] + b2r[i]);
            PP(wid, lg * 4 + i, qg, half * 16 + l15) =
                (u16)(__builtin_bit_cast(unsigned, e) >> 16);
          }
        }
      }
    }
    // wave-private P_s: in-wave DS ordering suffices (no barrier)

    // PV (16x16x32, K=32 own keys) + L (ones-A trick)
    s16x8 paf[8];
    #pragma unroll
    for (int h = 0; h < 8; ++h)
      paf[h] = *(const s16x8*)&PP(wid, h, l15, lg * 8);
    #pragma unroll
    for (int dc = 0; dc < 16; ++dc) {
      const s16x8 bv = *(const s16x8*)&vT[((size_t)(m * 256 + dc * 16 + l15)) * 1024 + kgb + lg * 8];
      acc2[dc] = MFMA16(paf[dc >> 1], bv, acc2[dc], 0, 0, 0);
    }
    #pragma unroll
    for (int h = 0; h < 8; ++h) {
      const f32x4 lc = MFMA16(onesA, paf[h], Z4, 0, 0, 0);
      Lacc[h] += lc[0];
    }
  }

  // ---- epilogue: block-local reduction of 4 wave-partials ----
  __syncthreads();  // all waves done with their P_s
  // stage: O as bf16 [4w][16q][256d] at lds[0..32768 B); L f32 [4][16][8] after
  u16* stg = &lds[0];
  float* stgL = (float*)&lds[16384];  // byte offset 32768
  #pragma unroll
  for (int dc = 0; dc < 16; ++dc)
    #pragma unroll
    for (int i = 0; i < 4; ++i)
      stg[(wid * 16 + lg * 4 + i) * 256 + dc * 16 + l15] = f2b(acc2[dc][i]);
  if (lg == 0) {
    #pragma unroll
    for (int h = 0; h < 8; ++h) stgL[(wid * 16 + l15) * 8 + h] = Lacc[h];
  }
  __syncthreads();
  {
    const int q = tid >> 4, dsg = (tid & 15) * 16;
    float v[16];
    #pragma unroll
    for (int j = 0; j < 16; ++j) v[j] = 0.0f;
    #pragma unroll
    for (int w = 0; w < 4; ++w) {
      const s16x8 c0 = *(const s16x8*)&stg[(w * 16 + q) * 256 + dsg];
      const s16x8 c1 = *(const s16x8*)&stg[(w * 16 + q) * 256 + dsg + 8];
      #pragma unroll
      for (int j = 0; j < 8; ++j) { v[j] += b2f((u16)c0[j]); v[8 + j] += b2f((u16)c1[j]); }
    }
    s16x8 o0, o1;
    #pragma unroll
    for (int j = 0; j < 8; ++j) { o0[j] = (short)f2b(v[j]); o1[j] = (short)f2b(v[8 + j]); }
    u16* dst = &myPre[((size_t)(m * 1024 + q0 + q)) * 256 + dsg];
    *(s16x8*)&dst[0] = o0;
    *(s16x8*)&dst[8] = o1;
  }
  if (tid < 128) {
    const int q = tid >> 3, h = tid & 7;
    float Ls = 0.0f;
    #pragma unroll
    for (int w = 0; w < 4; ++w) Ls += stgL[(w * 16 + q) * 8 + h];
    myL[((size_t)(m * 1024 + q0 + q)) * 8 + h] = Ls;
  }
  #undef PP
}

// ---------------- output projection with 2-way partial combine -------------
__global__ __launch_bounds__(256) void outp_kernel(
    const u16* __restrict__ preP, const float* __restrict__ Lb,
    const u16* __restrict__ WoT,
    const float* __restrict__ bout, float* __restrict__ out) {
  const int n0 = blockIdx.x * 64;
  const int j0 = blockIdx.y * 64;
  const int tid = threadIdx.x;
  const int lane = tid & 63, wid = tid >> 6;
  const int l15 = lane & 15, lg = lane >> 4;
  const int wn = wid & 1, wj = wid >> 1;
  __shared__ u16 As[64][40];
  __shared__ u16 Bs[64][40];
  f32x4 acc[2][2];
  #pragma unroll
  for (int a = 0; a < 2; ++a)
    #pragma unroll
    for (int b = 0; b < 2; ++b) acc[a][b] = (f32x4){0.f, 0.f, 0.f, 0.f};

  const size_t PSTRIDE = (size_t)8192 * 256;
  const size_t LSTRIDE = (size_t)8192 * 8;

  for (int ks = 0; ks < 8; ++ks) {
    const int d0 = ks * 32;
    const int r = tid >> 2, cb = (tid & 3) * 8;
    const size_t row = (size_t)(n0 + r);
    const float Ls = Lb[row * 8 + ks] + Lb[LSTRIDE + row * 8 + ks];
    const float inv = 1.0f / Ls;
    const s16x8 p0 = *(const s16x8*)&preP[row * 256 + d0 + cb];
    const s16x8 p1 = *(const s16x8*)&preP[PSTRIDE + row * 256 + d0 + cb];
    s16x8 t;
    #pragma unroll
    for (int j = 0; j < 8; ++j)
      t[j] = (short)f2b((b2f((u16)p0[j]) + b2f((u16)p1[j])) * inv);
    *(s16x8*)&As[r][cb] = t;
    *(s16x8*)&Bs[r][cb] = *(const s16x8*)&WoT[(size_t)(j0 + r) * 256 + d0 + cb];
    __syncthreads();
    s16x8 a0 = *(const s16x8*)&As[wn * 32 + l15][lg * 8];
    s16x8 a1 = *(const s16x8*)&As[wn * 32 + 16 + l15][lg * 8];
    s16x8 b0 = *(const s16x8*)&Bs[wj * 32 + l15][lg * 8];
    s16x8 b1 = *(const s16x8*)&Bs[wj * 32 + 16 + l15][lg * 8];
    acc[0][0] = MFMA16(a0, b0, acc[0][0], 0, 0, 0);
    acc[0][1] = MFMA16(a0, b1, acc[0][1], 0, 0, 0);
    acc[1][0] = MFMA16(a1, b0, acc[1][0], 0, 0, 0);
    acc[1][1] = MFMA16(a1, b1, acc[1][1], 0, 0, 0);
    __syncthreads();
  }
  #pragma unroll
  for (int sn = 0; sn < 2; ++sn)
    #pragma unroll
    for (int sj = 0; sj < 2; ++sj)
      #pragma unroll
      for (int i = 0; i < 4; ++i) {
        int n = n0 + wn * 32 + sn * 16 + lg * 4 + i;
        int j = j0 + wj * 32 + sj * 16 + l15;
        out[(size_t)n * 256 + j] = acc[sn][sj][i] + bout[j];
      }
}

extern "C" void kernel_launch(void* const* d_in, const int* in_sizes, int n_in,
                              void* d_out, int out_size, void* d_ws, size_t ws_size,
                              hipStream_t stream) {
  const float* zq = (const float*)d_in[0];
  const float* zk = (const float*)d_in[1];
  const float* zv = (const float*)d_in[2];
  const float* xq = (const float*)d_in[3];
  const float* xkv = (const float*)d_in[4];
  const float* Wq = (const float*)d_in[5];
  const float* Wk = (const float*)d_in[6];
  const float* Wv = (const float*)d_in[7];
  const float* Wo = (const float*)d_in[8];
  const float* bout = (const float*)d_in[9];
  const float* W1 = (const float*)d_in[10];
  const float* b1 = (const float*)d_in[11];
  const float* W2 = (const float*)d_in[12];
  const float* b2 = (const float*)d_in[13];
  float* out = (float*)d_out;

  const size_t MB = (size_t)1 << 20;
  char* ws = (char*)d_ws;
  u16* qb   = (u16*)(ws + 0 * MB);
  u16* kb   = (u16*)(ws + 4 * MB);
  u16* vT   = (u16*)(ws + 8 * MB);
  u16* preP = (u16*)(ws + 12 * MB);      // 2 x 4 MB bf16 partial O
  float* Lb = (float*)(ws + 20 * MB);    // 2 x 256 KB f32 partial L
  char* wbase = ws + 20 * MB + (512 << 10);
  u16* WqT  = (u16*)(wbase + 0 * (128 << 10));
  u16* WkT  = (u16*)(wbase + 1 * (128 << 10));
  u16* WvT  = (u16*)(wbase + 2 * (128 << 10));
  u16* WoT  = (u16*)(wbase + 3 * (128 << 10));

  wtrans_kernel<<<dim3(4, 256), dim3(256), 0, stream>>>(Wq, Wk, Wv, Wo, WqT, WkT, WvT, WoT);
  proj_kernel<<<dim3(128, 4, 3), dim3(256), 0, stream>>>(zq, zk, zv, WqT, WkT, WvT, qb, kb, vT);
  attn_kernel<<<dim3(1024), dim3(256), 0, stream>>>(qb, kb, vT, xq, xkv, W1, b1, W2, b2, preP, Lb);
  outp_kernel<<<dim3(128, 4), dim3(256), 0, stream>>>(preP, Lb, WoT, bout, out);
  copyxq_kernel<<<dim3(64), dim3(256), 0, stream>>>(xq, out + (size_t)8 * 1024 * 256);
}